// Round 5
// baseline (511.440 us; speedup 1.0000x reference)
//
#include <hip/hip_runtime.h>
#include <hip/hip_bf16.h>

#define DM   1024
#define NE   8
#define DFF  4096
#define NTOK 4096

typedef __attribute__((ext_vector_type(8))) short bf16x8;
typedef __attribute__((ext_vector_type(4))) float f32x4;

__device__ __forceinline__ short to_bf16(float f) {
  unsigned u = __float_as_uint(f);
  unsigned r = (u + 0x7fffu + ((u >> 16) & 1u)) >> 16;   // RNE
  return (short)r;
}

__device__ __forceinline__ void gl16(const void* g, void* l) {
  __builtin_amdgcn_global_load_lds(
      (const __attribute__((address_space(1))) unsigned*)g,
      (__attribute__((address_space(3))) unsigned*)l, 16, 0, 0);
}

#define DSB do { __builtin_amdgcn_s_barrier(); __builtin_amdgcn_sched_barrier(0); } while (0)

// ---------------- router ----------------
__global__ __launch_bounds__(256) void router_kernel(
    const float* __restrict__ x, const float* __restrict__ gw,
    int* __restrict__ cnt, float* __restrict__ psum,
    int* __restrict__ pairs, float* __restrict__ pairW)
{
  __shared__ float gws[DM * NE];
  const int tid = threadIdx.x;
  for (int i = tid * 4; i < DM * NE; i += 256 * 4)
    *reinterpret_cast<float4*>(&gws[i]) = *reinterpret_cast<const float4*>(&gw[i]);
  __syncthreads();

  const int n = blockIdx.x * 256 + tid;
  float acc[NE];
#pragma unroll
  for (int e = 0; e < NE; ++e) acc[e] = 0.f;

  const float4* xr = reinterpret_cast<const float4*>(x + (size_t)n * DM);
  for (int d4 = 0; d4 < DM / 4; ++d4) {
    float4 v = xr[d4];
    const float* gp = &gws[d4 * 4 * NE];
    float xv;
#pragma unroll
    for (int dd = 0; dd < 4; ++dd) {
      xv = (dd == 0) ? v.x : (dd == 1) ? v.y : (dd == 2) ? v.z : v.w;
#pragma unroll
      for (int e = 0; e < NE; ++e) acc[e] = fmaf(xv, gp[dd * NE + e], acc[e]);
    }
  }

  float mx = acc[0];
#pragma unroll
  for (int e = 1; e < NE; ++e) mx = fmaxf(mx, acc[e]);
  float p[NE], s = 0.f;
#pragma unroll
  for (int e = 0; e < NE; ++e) { p[e] = expf(acc[e] - mx); s += p[e]; }
  float inv = 1.f / s;
#pragma unroll
  for (int e = 0; e < NE; ++e) {
    float v = p[e] * inv;
#pragma unroll
    for (int o = 32; o > 0; o >>= 1) v += __shfl_xor(v, o);
    if ((tid & 63) == 0) atomicAdd(&psum[e], v);
  }

  float v0 = -1e30f, v1 = -1e30f; int i0 = 0, i1 = 0;
#pragma unroll
  for (int e = 0; e < NE; ++e) {
    float l = acc[e];
    if (l > v0) { v1 = v0; i1 = i0; v0 = l; i0 = e; }
    else if (l > v1) { v1 = l; i1 = e; }
  }
  float e1 = expf(v1 - v0);
  float den = 1.f + e1;
  pairW[n * 2]     = 1.f / den;
  pairW[n * 2 + 1] = e1 / den;
  int p0 = atomicAdd(&cnt[i0], 1); pairs[i0 * NTOK + p0] = n * 2;
  int p1 = atomicAdd(&cnt[i1], 1); pairs[i1 * NTOK + p1] = n * 2 + 1;
}

__global__ void finalize_kernel(const int* __restrict__ cnt, int* __restrict__ off,
                                const float* __restrict__ psum, float* __restrict__ aux)
{
  if (threadIdx.x == 0 && blockIdx.x == 0) {
    int o = 0;
    for (int e = 0; e < NE; ++e) { off[e] = o; o += cnt[e]; }
    off[NE] = o;
    float a = 0.f;
    for (int e = 0; e < NE; ++e) { float me = psum[e] * (1.f / NTOK); a += me * me; }
    aux[0] = a * (float)NE;
  }
}

// ---------------- prepass: x f32 -> bf16 ----------------
__global__ __launch_bounds__(256) void convert_x_kernel(
    const float* __restrict__ x, short* __restrict__ xb)
{
  const int i = (blockIdx.x * 256 + threadIdx.x) * 8;
  float4 a = *reinterpret_cast<const float4*>(&x[i]);
  float4 b = *reinterpret_cast<const float4*>(&x[i + 4]);
  union { short s[8]; bf16x8 v; } p;
  p.s[0]=to_bf16(a.x); p.s[1]=to_bf16(a.y); p.s[2]=to_bf16(a.z); p.s[3]=to_bf16(a.w);
  p.s[4]=to_bf16(b.x); p.s[5]=to_bf16(b.y); p.s[6]=to_bf16(b.z); p.s[7]=to_bf16(b.w);
  *reinterpret_cast<bf16x8*>(&xb[i]) = p.v;
}

// ---------------- prepass: transpose + convert weights ----------------
__global__ __launch_bounds__(256) void transpose_kernel(
    const float* __restrict__ w1, const float* __restrict__ w2,
    short* __restrict__ w1t, short* __restrict__ w2t)
{
  const int z = blockIdx.z;
  const float* src; short* dst; int R, C, rt, ct;
  if (z < 8) { src = w1 + (size_t)z * DM * DFF; dst = w1t + (size_t)z * DM * DFF;
               R = DM; C = DFF; ct = blockIdx.x; rt = blockIdx.y; }
  else       { src = w2 + (size_t)(z - 8) * DM * DFF; dst = w2t + (size_t)(z - 8) * DM * DFF;
               R = DFF; C = DM; ct = blockIdx.y; rt = blockIdx.x; }
  const int r0 = rt * 64, c0 = ct * 64;
  __shared__ float t[64][65];
  const int tid = threadIdx.x;
  {
    const int row = tid >> 4;
    const int col = (tid & 15) * 4;
#pragma unroll
    for (int it = 0; it < 4; ++it) {
      float4 v = *reinterpret_cast<const float4*>(&src[(size_t)(r0 + it * 16 + row) * C + c0 + col]);
      t[it * 16 + row][col]     = v.x;
      t[it * 16 + row][col + 1] = v.y;
      t[it * 16 + row][col + 2] = v.z;
      t[it * 16 + row][col + 3] = v.w;
    }
  }
  __syncthreads();
  {
    const int oc  = tid >> 3;
    const int orr = (tid & 7) * 8;
#pragma unroll
    for (int it = 0; it < 2; ++it) {
      union { short s[8]; bf16x8 v; } p;
#pragma unroll
      for (int j = 0; j < 8; ++j) p.s[j] = to_bf16(t[orr + j][it * 32 + oc]);
      *reinterpret_cast<bf16x8*>(&dst[(size_t)(c0 + it * 32 + oc) * R + r0 + orr]) = p.v;
    }
  }
}

// ============ 256x256xBK64 8-phase schedule, 8 waves (4 wm x 2 wn) ============
// LDS per buf: A 256x64 bf16 (32KB, rows of 8 16B-chunks, chunk ^= row&7), B same.
// Stage quanta (8 gl16/thread/tile): rA0-3 (A rows r*64..), rB0-3 (B rows r*64..).
// Issue for tile T+1 during tile T:  ph0: rA0-3 | ph1: rB0,rB2 | ph2: rB1,rB3.
// Consumption of tile T: ph0 needs rA*,rB0,rB2 ; ph2 needs rB1,rB3.
// vmcnt ledger (oldest-first FIFO): end-ph1: pending = T{rB1,rB3} + (T+1){rA*,rB0,rB2}
//   = 8 -> vmcnt(6) lands T's rB1,rB3.  end-ph3: pending = (T+1) all 8 -> vmcnt(2)
//   lands rA*,rB0,rB2 of T+1 (rB1,rB3 stay in flight). Last tile: vmcnt(0)/skip.

#define GEMM_CORE(A_PTRS, B_PTRS)                                                        \
  __shared__ short As[2][16384];                                                         \
  __shared__ short Bs[2][16384];                                                         \
  const int lane = tid & 63;                                                             \
  const int wv = tid >> 6, wm = wv >> 1, wn = wv & 1;                                    \
  const int ldst = tid * 16;                                                             \
  const int cx0 = (lane >> 4) ^ (lane & 7);                                              \
  const int cxk0 = cx0 << 4, cxk1 = (cx0 ^ 4) << 4;                                      \
  const int abase = (wm * 64 + (lane & 15)) * 128;                                       \
  const int bbase = (wn * 128 + (lane & 15)) * 128;                                      \
  f32x4 acc[4][8];                                                                       \
  _Pragma("unroll") for (int i = 0; i < 4; ++i)                                          \
    _Pragma("unroll") for (int j = 0; j < 8; ++j) acc[i][j] = (f32x4){0.f,0.f,0.f,0.f};  \
  { /* prologue: stage tile 0 into buf 0 */                                              \
    char* A0 = (char*)As[0]; char* B0 = (char*)Bs[0];                                    \
    gl16(gA[0], A0 + 0*8192 + ldst); gl16(gA[1], A0 + 1*8192 + ldst);                    \
    gl16(gA[2], A0 + 2*8192 + ldst); gl16(gA[3], A0 + 3*8192 + ldst);                    \
    gl16(gB[0], B0 + 0*8192 + ldst); gl16(gB[2], B0 + 2*8192 + ldst);                    \
    gl16(gB[1], B0 + 1*8192 + ldst); gl16(gB[3], B0 + 3*8192 + ldst);                    \
    asm volatile("s_waitcnt vmcnt(2)" ::: "memory");                                     \
    DSB;                                                                                 \
  }                                                                                      \
  for (int T = 0; T < 16; ++T) {                                                         \
    const bool S = (T < 15);                                                             \
    const char* Acb = (const char*)As[T & 1];                                            \
    const char* Bcb = (const char*)Bs[T & 1];                                            \
    char* An = (char*)As[(T + 1) & 1];                                                   \
    char* Bn = (char*)Bs[(T + 1) & 1];                                                   \
    const int kn = (T + 1) * 64;                                                         \
    bf16x8 afr[4][2], bf[2][2];                                                          \
    /* ---- phase 0 ---- */                                                              \
    _Pragma("unroll") for (int i = 0; i < 4; ++i) {                                      \
      afr[i][0] = *(const bf16x8*)(Acb + abase + i*2048 + cxk0);                         \
      afr[i][1] = *(const bf16x8*)(Acb + abase + i*2048 + cxk1);                         \
    }                                                                                    \
    _Pragma("unroll") for (int j2 = 0; j2 < 2; ++j2) {                                   \
      bf[j2][0] = *(const bf16x8*)(Bcb + bbase + j2*2048 + cxk0);                        \
      bf[j2][1] = *(const bf16x8*)(Bcb + bbase + j2*2048 + cxk1);                        \
    }                                                                                    \
    if (S) { gl16(gA[0]+kn, An+0*8192+ldst); gl16(gA[1]+kn, An+1*8192+ldst);             \
             gl16(gA[2]+kn, An+2*8192+ldst); gl16(gA[3]+kn, An+3*8192+ldst); }           \
    DSB;                                                                                 \
    __builtin_amdgcn_s_setprio(1);                                                       \
    _Pragma("unroll") for (int i = 0; i < 4; ++i)                                        \
      _Pragma("unroll") for (int j2 = 0; j2 < 2; ++j2) {                                 \
        acc[i][j2] = __builtin_amdgcn_mfma_f32_16x16x32_bf16(afr[i][0], bf[j2][0], acc[i][j2], 0,0,0); \
        acc[i][j2] = __builtin_amdgcn_mfma_f32_16x16x32_bf16(afr[i][1], bf[j2][1], acc[i][j2], 0,0,0); \
      }                                                                                  \
    __builtin_amdgcn_s_setprio(0);                                                       \
    DSB;                                                                                 \
    /* ---- phase 1 ---- */                                                              \
    _Pragma("unroll") for (int j2 = 0; j2 < 2; ++j2) {                                   \
      bf[j2][0] = *(const bf16x8*)(Bcb + bbase + (2+j2)*2048 + cxk0);                    \
      bf[j2][1] = *(const bf16x8*)(Bcb + bbase + (2+j2)*2048 + cxk1);                    \
    }                                                                                    \
    if (S) { gl16(gB[0]+kn, Bn+0*8192+ldst); gl16(gB[2]+kn, Bn+2*8192+ldst); }           \
    DSB;                                                                                 \
    __builtin_amdgcn_s_setprio(1);                                                       \
    _Pragma("unroll") for (int i = 0; i < 4; ++i)                                        \
      _Pragma("unroll") for (int j2 = 0; j2 < 2; ++j2) {                                 \
        acc[i][2+j2] = __builtin_amdgcn_mfma_f32_16x16x32_bf16(afr[i][0], bf[j2][0], acc[i][2+j2], 0,0,0); \
        acc[i][2+j2] = __builtin_amdgcn_mfma_f32_16x16x32_bf16(afr[i][1], bf[j2][1], acc[i][2+j2], 0,0,0); \
      }                                                                                  \
    __builtin_amdgcn_s_setprio(0);                                                       \
    if (S) { asm volatile("s_waitcnt vmcnt(6)" ::: "memory"); }                          \
    else   { asm volatile("s_waitcnt vmcnt(0)" ::: "memory"); }                          \
    DSB;                                                                                 \
    /* ---- phase 2 ---- */                                                              \
    _Pragma("unroll") for (int j2 = 0; j2 < 2; ++j2) {                                   \
      bf[j2][0] = *(const bf16x8*)(Bcb + bbase + (4+j2)*2048 + cxk0);                    \
      bf[j2][1] = *(const bf16x8*)(Bcb + bbase + (4+j2)*2048 + cxk1);                    \
    }                                                                                    \
    if (S) { gl16(gB[1]+kn, Bn+1*8192+ldst); gl16(gB[3]+kn, Bn+3*8192+ldst); }           \
    DSB;                                                                                 \
    __builtin_amdgcn_s_setprio(1);                                                       \
    _Pragma("unroll") for (int i = 0; i < 4; ++i)                                        \
      _Pragma("unroll") for (int j2 = 0; j2 < 2; ++j2) {                                 \
        acc[i][4+j2] = __builtin_amdgcn_mfma_f32_16x16x32_bf16(afr[i][0], bf[j2][0], acc[i][4+j2], 0,0,0); \
        acc[i][4+j2] = __builtin_amdgcn_mfma_f32_16x16x32_bf16(afr[i][1], bf[j2][1], acc[i][4+j2], 0,0,0); \
      }                                                                                  \
    __builtin_amdgcn_s_setprio(0);                                                       \
    DSB;                                                                                 \
    /* ---- phase 3 ---- */                                                              \
    _Pragma("unroll") for (int j2 = 0; j2 < 2; ++j2) {                                   \
      bf[j2][0] = *(const bf16x8*)(Bcb + bbase + (6+j2)*2048 + cxk0);                    \
      bf[j2][1] = *(const bf16x8*)(Bcb + bbase + (6+j2)*2048 + cxk1);                    \
    }                                                                                    \
    DSB;                                                                                 \
    __builtin_amdgcn_s_setprio(1);                                                       \
    _Pragma("unroll") for (int i = 0; i < 4; ++i)                                        \
      _Pragma("unroll") for (int j2 = 0; j2 < 2; ++j2) {                                 \
        acc[i][6+j2] = __builtin_amdgcn_mfma_f32_16x16x32_bf16(afr[i][0], bf[j2][0], acc[i][6+j2], 0,0,0); \
        acc[i][6+j2] = __builtin_amdgcn_mfma_f32_16x16x32_bf16(afr[i][1], bf[j2][1], acc[i][6+j2], 0,0,0); \
      }                                                                                  \
    __builtin_amdgcn_s_setprio(0);                                                       \
    if (S) { asm volatile("s_waitcnt vmcnt(2)" ::: "memory"); }                          \
    DSB;                                                                                 \
  }

// ======== GEMM1: h = gelu(gather(xb) @ w1t[e]^T) ========
__global__ __launch_bounds__(512, 2) void gemm1_kernel(
    const short* __restrict__ xb, const short* __restrict__ w1t,
    const int* __restrict__ cnt, const int* __restrict__ off,
    const int* __restrict__ pairs, short* __restrict__ h)
{
  const int wg = (blockIdx.x & 7) * 256 + (blockIdx.x >> 3);   // nwg=2048, bijective
  const int mt = wg & 15;
  const int e  = (wg >> 4) & 7;
  const int ft = wg >> 7;
  const int M  = cnt[e];
  const int m0 = mt * 256;
  if (m0 >= M) return;
  const int ff0  = ft * 256;
  const int base = off[e];
  const int tid  = threadIdx.x;

  // staging sources
  const int srow = tid >> 3;
  const short* gA[4]; const short* gB[4];
#pragma unroll
  for (int r = 0; r < 4; ++r) {
    const int row = r * 64 + srow;
    const int ch  = (tid & 7) ^ (row & 7);
    int gi = m0 + row; if (gi > M - 1) gi = M - 1;
    const int tok = pairs[e * NTOK + gi] >> 1;
    gA[r] = xb + (size_t)tok * DM + ch * 8;
    gB[r] = w1t + ((size_t)e * DFF + ff0 + row) * DM + ch * 8;
  }

  GEMM_CORE(gA, gB)

  const int erow0 = m0 + wm * 64 + (lane >> 4) * 4;
  const int ecol0 = ff0 + wn * 128 + (lane & 15);
#pragma unroll
  for (int i = 0; i < 4; ++i) {
#pragma unroll
    for (int r = 0; r < 4; ++r) {
      const int grow = erow0 + i * 16 + r;
      if (grow < M) {
        short* hp = h + (size_t)(base + grow) * DFF + ecol0;
#pragma unroll
        for (int j = 0; j < 8; ++j) {
          float v = acc[i][j][r];
          float g = 0.5f * v * (1.f + erff(v * 0.70710678118f));
          hp[j * 16] = to_bf16(g);
        }
      }
    }
  }
}

// ======== GEMM2: out += w * (h @ w2t[e]^T), split-K=4 ========
__global__ __launch_bounds__(512, 2) void gemm2_kernel(
    const short* __restrict__ h, const short* __restrict__ w2t,
    const int* __restrict__ cnt, const int* __restrict__ off,
    const int* __restrict__ pairs, const float* __restrict__ pairW,
    float* __restrict__ out)
{
  const int wg = (blockIdx.x & 7) * 256 + (blockIdx.x >> 3);   // nwg=2048
  const int mt = wg & 15;
  const int e  = (wg >> 4) & 7;
  const int z  = wg >> 7;          // 0..15
  const int dt = z & 3;
  const int kh = z >> 2;           // 0..3
  const int M  = cnt[e];
  const int m0 = mt * 256;
  if (m0 >= M) return;
  const int d0    = dt * 256;
  const int kbase = kh * 1024;
  const int base  = off[e];
  const int tid   = threadIdx.x;

  const int srow = tid >> 3;
  const short* gA[4]; const short* gB[4];
#pragma unroll
  for (int r = 0; r < 4; ++r) {
    const int row = r * 64 + srow;
    const int ch  = (tid & 7) ^ (row & 7);
    int gi = m0 + row; if (gi > M - 1) gi = M - 1;
    gA[r] = h + (size_t)(base + gi) * DFF + kbase + ch * 8;
    gB[r] = w2t + ((size_t)e * DM + d0 + row) * DFF + kbase + ch * 8;
  }

  GEMM_CORE(gA, gB)

  const int erow0 = m0 + wm * 64 + (lane >> 4) * 4;
  const int ecol0 = d0 + wn * 128 + (lane & 15);
#pragma unroll
  for (int i = 0; i < 4; ++i) {
#pragma unroll
    for (int r = 0; r < 4; ++r) {
      const int grow = erow0 + i * 16 + r;
      if (grow < M) {
        const int pr    = pairs[e * NTOK + grow];
        const float wgt = pairW[pr];
        const int tok   = pr >> 1;
        float* op = out + (size_t)tok * DM + ecol0;
#pragma unroll
        for (int j = 0; j < 8; ++j)
          atomicAdd(&op[j * 16], wgt * acc[i][j][r]);
      }
    }
  }
}

extern "C" void kernel_launch(void* const* d_in, const int* in_sizes, int n_in,
                              void* d_out, int out_size, void* d_ws, size_t ws_size,
                              hipStream_t stream)
{
  const float* x  = (const float*)d_in[0];
  const float* gw = (const float*)d_in[1];
  const float* w1 = (const float*)d_in[2];
  const float* w2 = (const float*)d_in[3];
  float* outf = (float*)d_out;

  int*   cnt   = (int*)d_ws;
  int*   off   = cnt + 8;
  float* psum  = (float*)(cnt + 20);
  int*   pairs = (int*)((char*)d_ws + 512);
  float* pairW = (float*)((char*)d_ws + 512 + NE * NTOK * 4);
  short* xb    = (short*)((char*)d_ws + (size_t)(1)  * (1 << 20));
  short* w1t   = (short*)((char*)d_ws + (size_t)(16) * (1 << 20));
  short* w2t   = (short*)((char*)d_ws + (size_t)(80) * (1 << 20));
  short* h     = (short*)((char*)d_ws + (size_t)(144)* (1 << 20));

  hipMemsetAsync(d_ws, 0, 512, stream);
  hipMemsetAsync(d_out, 0, (size_t)out_size * sizeof(float), stream);

  router_kernel<<<NTOK / 256, 256, 0, stream>>>(x, gw, cnt, psum, pairs, pairW);
  finalize_kernel<<<1, 64, 0, stream>>>(cnt, off, psum, outf + (size_t)NTOK * DM);
  convert_x_kernel<<<NTOK * DM / (256 * 8), 256, 0, stream>>>(x, xb);
  transpose_kernel<<<dim3(64, 16, 16), 256, 0, stream>>>(w1, w2, w1t, w2t);
  gemm1_kernel<<<2048, 512, 0, stream>>>(xb, w1t, cnt, off, pairs, h);
  gemm2_kernel<<<2048, 512, 0, stream>>>(h, w2t, cnt, off, pairs, pairW, outf);
}

// Round 6
// 457.987 us; speedup vs baseline: 1.1167x; 1.1167x over previous
//
#include <hip/hip_runtime.h>
#include <hip/hip_bf16.h>

#define DM   1024
#define NE   8
#define DFF  4096
#define NTOK 4096

typedef __attribute__((ext_vector_type(8))) short bf16x8;
typedef __attribute__((ext_vector_type(4))) float f32x4;

__device__ __forceinline__ short to_bf16(float f) {
  unsigned u = __float_as_uint(f);
  unsigned r = (u + 0x7fffu + ((u >> 16) & 1u)) >> 16;   // RNE
  return (short)r;
}

__device__ __forceinline__ void gl16(const void* g, void* l) {
  __builtin_amdgcn_global_load_lds(
      (const __attribute__((address_space(1))) unsigned*)g,
      (__attribute__((address_space(3))) unsigned*)l, 16, 0, 0);
}

#define DSB do { __builtin_amdgcn_s_barrier(); __builtin_amdgcn_sched_barrier(0); } while (0)

// ---------------- router ----------------
__global__ __launch_bounds__(256) void router_kernel(
    const float* __restrict__ x, const float* __restrict__ gw,
    int* __restrict__ cnt, float* __restrict__ psum,
    int* __restrict__ pairs, float* __restrict__ pairW)
{
  __shared__ float gws[DM * NE];
  const int tid = threadIdx.x;
  for (int i = tid * 4; i < DM * NE; i += 256 * 4)
    *reinterpret_cast<float4*>(&gws[i]) = *reinterpret_cast<const float4*>(&gw[i]);
  __syncthreads();

  const int n = blockIdx.x * 256 + tid;
  float acc[NE];
#pragma unroll
  for (int e = 0; e < NE; ++e) acc[e] = 0.f;

  const float4* xr = reinterpret_cast<const float4*>(x + (size_t)n * DM);
  for (int d4 = 0; d4 < DM / 4; ++d4) {
    float4 v = xr[d4];
    const float* gp = &gws[d4 * 4 * NE];
    float xv;
#pragma unroll
    for (int dd = 0; dd < 4; ++dd) {
      xv = (dd == 0) ? v.x : (dd == 1) ? v.y : (dd == 2) ? v.z : v.w;
#pragma unroll
      for (int e = 0; e < NE; ++e) acc[e] = fmaf(xv, gp[dd * NE + e], acc[e]);
    }
  }

  float mx = acc[0];
#pragma unroll
  for (int e = 1; e < NE; ++e) mx = fmaxf(mx, acc[e]);
  float p[NE], s = 0.f;
#pragma unroll
  for (int e = 0; e < NE; ++e) { p[e] = expf(acc[e] - mx); s += p[e]; }
  float inv = 1.f / s;
#pragma unroll
  for (int e = 0; e < NE; ++e) {
    float v = p[e] * inv;
#pragma unroll
    for (int o = 32; o > 0; o >>= 1) v += __shfl_xor(v, o);
    if ((tid & 63) == 0) atomicAdd(&psum[e], v);
  }

  float v0 = -1e30f, v1 = -1e30f; int i0 = 0, i1 = 0;
#pragma unroll
  for (int e = 0; e < NE; ++e) {
    float l = acc[e];
    if (l > v0) { v1 = v0; i1 = i0; v0 = l; i0 = e; }
    else if (l > v1) { v1 = l; i1 = e; }
  }
  float e1 = expf(v1 - v0);
  float den = 1.f + e1;
  pairW[n * 2]     = 1.f / den;
  pairW[n * 2 + 1] = e1 / den;
  int p0 = atomicAdd(&cnt[i0], 1); pairs[i0 * NTOK + p0] = n * 2;
  int p1 = atomicAdd(&cnt[i1], 1); pairs[i1 * NTOK + p1] = n * 2 + 1;
}

__global__ void finalize_kernel(const int* __restrict__ cnt, int* __restrict__ off,
                                const float* __restrict__ psum, float* __restrict__ aux)
{
  if (threadIdx.x == 0 && blockIdx.x == 0) {
    int o = 0;
    for (int e = 0; e < NE; ++e) { off[e] = o; o += cnt[e]; }
    off[NE] = o;
    float a = 0.f;
    for (int e = 0; e < NE; ++e) { float me = psum[e] * (1.f / NTOK); a += me * me; }
    aux[0] = a * (float)NE;
  }
}

// ---------------- prepass: x f32 -> bf16 ----------------
__global__ __launch_bounds__(256) void convert_x_kernel(
    const float* __restrict__ x, short* __restrict__ xb)
{
  const int i = (blockIdx.x * 256 + threadIdx.x) * 8;
  float4 a = *reinterpret_cast<const float4*>(&x[i]);
  float4 b = *reinterpret_cast<const float4*>(&x[i + 4]);
  union { short s[8]; bf16x8 v; } p;
  p.s[0]=to_bf16(a.x); p.s[1]=to_bf16(a.y); p.s[2]=to_bf16(a.z); p.s[3]=to_bf16(a.w);
  p.s[4]=to_bf16(b.x); p.s[5]=to_bf16(b.y); p.s[6]=to_bf16(b.z); p.s[7]=to_bf16(b.w);
  *reinterpret_cast<bf16x8*>(&xb[i]) = p.v;
}

// ---------------- prepass: transpose + convert weights ----------------
__global__ __launch_bounds__(256) void transpose_kernel(
    const float* __restrict__ w1, const float* __restrict__ w2,
    short* __restrict__ w1t, short* __restrict__ w2t)
{
  const int z = blockIdx.z;
  const float* src; short* dst; int R, C, rt, ct;
  if (z < 8) { src = w1 + (size_t)z * DM * DFF; dst = w1t + (size_t)z * DM * DFF;
               R = DM; C = DFF; ct = blockIdx.x; rt = blockIdx.y; }
  else       { src = w2 + (size_t)(z - 8) * DM * DFF; dst = w2t + (size_t)(z - 8) * DM * DFF;
               R = DFF; C = DM; ct = blockIdx.y; rt = blockIdx.x; }
  const int r0 = rt * 64, c0 = ct * 64;
  __shared__ float t[64][65];
  const int tid = threadIdx.x;
  {
    const int row = tid >> 4;
    const int col = (tid & 15) * 4;
#pragma unroll
    for (int it = 0; it < 4; ++it) {
      float4 v = *reinterpret_cast<const float4*>(&src[(size_t)(r0 + it * 16 + row) * C + c0 + col]);
      t[it * 16 + row][col]     = v.x;
      t[it * 16 + row][col + 1] = v.y;
      t[it * 16 + row][col + 2] = v.z;
      t[it * 16 + row][col + 3] = v.w;
    }
  }
  __syncthreads();
  {
    const int oc  = tid >> 3;
    const int orr = (tid & 7) * 8;
#pragma unroll
    for (int it = 0; it < 2; ++it) {
      union { short s[8]; bf16x8 v; } p;
#pragma unroll
      for (int j = 0; j < 8; ++j) p.s[j] = to_bf16(t[orr + j][it * 32 + oc]);
      *reinterpret_cast<bf16x8*>(&dst[(size_t)(c0 + it * 32 + oc) * R + r0 + orr]) = p.v;
    }
  }
}

// ======= 128x128xBK32 core, 4 waves, dbuf + depth-2 prefetch, counted vmcnt =======
// Per iter each thread issues 4 gl16 (2 A + 2 B). Pending at top of iter T =
// {T's 4, T+1's 4} = 8. vmcnt(4) lands T's loads (issued 2 iters ago, ~2600cy
// -> no stall). After compute, STAGE(buf[T&1], T+2) refills. Last iter: vmcnt(0).
// Cross-wave safety: a wave passes barrier#2 only after its MFMAs consumed the
// ds_read data (compiler lgkmcnt), so re-staging buf[cur] after barrier#2 is safe.
// LDS swizzle (proven R3, 0 conflicts): tile = [64 pairs][8 chunks of 8 shorts],
// chunk (p,s) holds (row = 2p + ((s^(p&7))>>2), kchunk = (s^(p&7))&3).

#define GEMM_LOOP(NT)                                                              \
  f32x4 acc[4][4];                                                                 \
  _Pragma("unroll") for (int i = 0; i < 4; ++i)                                    \
    _Pragma("unroll") for (int j = 0; j < 4; ++j) acc[i][j] = (f32x4){0.f,0.f,0.f,0.f}; \
  STAGE(0, 0);                                                                     \
  STAGE(1, 32);                                                                    \
  for (int t = 0; t < (NT); ++t) {                                                 \
    const int cur = t & 1;                                                         \
    if (t < (NT) - 1) { asm volatile("s_waitcnt vmcnt(4)" ::: "memory"); }         \
    else              { asm volatile("s_waitcnt vmcnt(0)" ::: "memory"); }         \
    DSB;                                                                           \
    bf16x8 af[4], bfv[4];                                                          \
    _Pragma("unroll") for (int i = 0; i < 4; ++i)                                  \
      af[i] = *reinterpret_cast<const bf16x8*>(&As[cur][ab + i * 512]);            \
    _Pragma("unroll") for (int j = 0; j < 4; ++j)                                  \
      bfv[j] = *reinterpret_cast<const bf16x8*>(&Bs[cur][bb + j * 512]);           \
    _Pragma("unroll") for (int i = 0; i < 4; ++i)                                  \
      _Pragma("unroll") for (int j = 0; j < 4; ++j)                                \
        acc[i][j] = __builtin_amdgcn_mfma_f32_16x16x32_bf16(af[i], bfv[j], acc[i][j], 0, 0, 0); \
    DSB;                                                                           \
    if (t + 2 < (NT)) STAGE(cur, (t + 2) * 32);                                    \
  }

// ======== GEMM1: h = gelu(gather(xb) @ w1t[e]^T) ========
__global__ __launch_bounds__(256) void gemm1_kernel(
    const short* __restrict__ xb, const short* __restrict__ w1t,
    const int* __restrict__ cnt, const int* __restrict__ off,
    const int* __restrict__ pairs, short* __restrict__ h)
{
  // bijective XCD swizzle, nwg=8192; decode: m inner(32), e mid(8), ff outer(32)
  const int wg = (blockIdx.x & 7) * 1024 + (blockIdx.x >> 3);
  const int mt  = wg & 31;
  const int e   = (wg >> 5) & 7;
  const int ft  = wg >> 8;
  const int M   = cnt[e];
  const int m0  = mt * 128;
  if (m0 >= M) return;
  const int ff0  = ft * 128;
  const int base = off[e];

  __shared__ __attribute__((aligned(16))) short As[2][128 * 32];
  __shared__ __attribute__((aligned(16))) short Bs[2][128 * 32];

  const int tid  = threadIdx.x;
  const int lane = tid & 63;
  const int wv   = tid >> 6;
  const int wm   = wv >> 1;
  const int wn   = wv & 1;

  const short* gA[2]; const short* gB[2]; int ldo[2];
#pragma unroll
  for (int l = 0; l < 2; ++l) {
    const int n   = l * 256 + tid;
    const int p   = n >> 3;
    const int s   = n & 7;
    const int cip = s ^ (p & 7);
    const int row = p * 2 + (cip >> 2);
    const int kch = cip & 3;
    int gi = m0 + row; if (gi > M - 1) gi = M - 1;
    const int tok = pairs[e * NTOK + gi] >> 1;
    gA[l]  = xb + (size_t)tok * DM + kch * 8;
    gB[l]  = w1t + ((size_t)e * DFF + ff0 + row) * DM + kch * 8;
    ldo[l] = n * 8;
  }

#define STAGE(buf, k0) do { \
  gl16(gA[0] + (k0), &As[buf][ldo[0]]); \
  gl16(gA[1] + (k0), &As[buf][ldo[1]]); \
  gl16(gB[0] + (k0), &Bs[buf][ldo[0]]); \
  gl16(gB[1] + (k0), &Bs[buf][ldo[1]]); \
} while (0)

  const int lrw = lane & 15;
  const int sr  = ((((lane & 1) << 2) | (lane >> 4)) ^ ((lane & 15) >> 1)) * 8;
  const int ab  = (wm * 32 + (lrw >> 1)) * 64 + sr;
  const int bb  = (wn * 32 + (lrw >> 1)) * 64 + sr;

  GEMM_LOOP(32)
#undef STAGE

  const int erow0 = m0 + wm * 64 + (lane >> 4) * 4;
  const int ecol0 = ff0 + wn * 64 + (lane & 15);
#pragma unroll
  for (int i = 0; i < 4; ++i) {
#pragma unroll
    for (int r = 0; r < 4; ++r) {
      const int grow = erow0 + i * 16 + r;
      if (grow < M) {
#pragma unroll
        for (int j = 0; j < 4; ++j) {
          float v = acc[i][j][r];
          float g = 0.5f * v * (1.f + erff(v * 0.70710678118f));
          h[(size_t)(base + grow) * DFF + ecol0 + j * 16] = to_bf16(g);
        }
      }
    }
  }
}

// ======== GEMM2: out += w * (h @ w2t[e]^T), K=4096, no split-K ========
__global__ __launch_bounds__(256) void gemm2_kernel(
    const short* __restrict__ h, const short* __restrict__ w2t,
    const int* __restrict__ cnt, const int* __restrict__ off,
    const int* __restrict__ pairs, const float* __restrict__ pairW,
    float* __restrict__ out)
{
  // nwg=2048; decode: m inner(32), e mid(8), dt outer(8)
  const int wg = (blockIdx.x & 7) * 256 + (blockIdx.x >> 3);
  const int mt = wg & 31;
  const int e  = (wg >> 5) & 7;
  const int dt = wg >> 8;
  const int M  = cnt[e];
  const int m0 = mt * 128;
  if (m0 >= M) return;
  const int d0   = dt * 128;
  const int base = off[e];

  __shared__ __attribute__((aligned(16))) short As[2][128 * 32];
  __shared__ __attribute__((aligned(16))) short Bs[2][128 * 32];

  const int tid  = threadIdx.x;
  const int lane = tid & 63;
  const int wv   = tid >> 6;
  const int wm   = wv >> 1;
  const int wn   = wv & 1;

  const short* gA[2]; const short* gB[2]; int ldo[2];
#pragma unroll
  for (int l = 0; l < 2; ++l) {
    const int n   = l * 256 + tid;
    const int p   = n >> 3;
    const int s   = n & 7;
    const int cip = s ^ (p & 7);
    const int row = p * 2 + (cip >> 2);
    const int kch = cip & 3;
    int gi = m0 + row; if (gi > M - 1) gi = M - 1;
    gA[l]  = h + (size_t)(base + gi) * DFF + kch * 8;
    gB[l]  = w2t + ((size_t)e * DM + d0 + row) * DFF + kch * 8;
    ldo[l] = n * 8;
  }

#define STAGE(buf, k0) do { \
  gl16(gA[0] + (k0), &As[buf][ldo[0]]); \
  gl16(gA[1] + (k0), &As[buf][ldo[1]]); \
  gl16(gB[0] + (k0), &Bs[buf][ldo[0]]); \
  gl16(gB[1] + (k0), &Bs[buf][ldo[1]]); \
} while (0)

  const int lrw = lane & 15;
  const int sr  = ((((lane & 1) << 2) | (lane >> 4)) ^ ((lane & 15) >> 1)) * 8;
  const int ab  = (wm * 32 + (lrw >> 1)) * 64 + sr;
  const int bb  = (wn * 32 + (lrw >> 1)) * 64 + sr;

  GEMM_LOOP(128)
#undef STAGE

  const int erow0 = m0 + wm * 64 + (lane >> 4) * 4;
  const int ecol0 = d0 + wn * 64 + (lane & 15);
#pragma unroll
  for (int i = 0; i < 4; ++i) {
#pragma unroll
    for (int r = 0; r < 4; ++r) {
      const int grow = erow0 + i * 16 + r;
      if (grow < M) {
        const int pr    = pairs[e * NTOK + grow];
        const float wgt = pairW[pr];
        const int tok   = pr >> 1;
#pragma unroll
        for (int j = 0; j < 4; ++j)
          atomicAdd(&out[(size_t)tok * DM + ecol0 + j * 16], wgt * acc[i][j][r]);
      }
    }
  }
}

extern "C" void kernel_launch(void* const* d_in, const int* in_sizes, int n_in,
                              void* d_out, int out_size, void* d_ws, size_t ws_size,
                              hipStream_t stream)
{
  const float* x  = (const float*)d_in[0];
  const float* gw = (const float*)d_in[1];
  const float* w1 = (const float*)d_in[2];
  const float* w2 = (const float*)d_in[3];
  float* outf = (float*)d_out;

  int*   cnt   = (int*)d_ws;
  int*   off   = cnt + 8;
  float* psum  = (float*)(cnt + 20);
  int*   pairs = (int*)((char*)d_ws + 512);
  float* pairW = (float*)((char*)d_ws + 512 + NE * NTOK * 4);
  short* xb    = (short*)((char*)d_ws + (size_t)(1)  * (1 << 20));
  short* w1t   = (short*)((char*)d_ws + (size_t)(16) * (1 << 20));
  short* w2t   = (short*)((char*)d_ws + (size_t)(80) * (1 << 20));
  short* h     = (short*)((char*)d_ws + (size_t)(144)* (1 << 20));

  hipMemsetAsync(d_ws, 0, 512, stream);
  hipMemsetAsync(d_out, 0, (size_t)out_size * sizeof(float), stream);

  router_kernel<<<NTOK / 256, 256, 0, stream>>>(x, gw, cnt, psum, pairs, pairW);
  finalize_kernel<<<1, 64, 0, stream>>>(cnt, off, psum, outf + (size_t)NTOK * DM);
  convert_x_kernel<<<NTOK * DM / (256 * 8), 256, 0, stream>>>(x, xb);
  transpose_kernel<<<dim3(64, 16, 16), 256, 0, stream>>>(w1, w2, w1t, w2t);
  gemm1_kernel<<<8192, 256, 0, stream>>>(xb, w1t, cnt, off, pairs, h);
  gemm2_kernel<<<2048, 256, 0, stream>>>(h, w2t, cnt, off, pairs, pairW, outf);
}

// Round 7
// 396.237 us; speedup vs baseline: 1.2907x; 1.1558x over previous
//
#include <hip/hip_runtime.h>
#include <hip/hip_bf16.h>

#define DM   1024
#define NE   8
#define DFF  4096
#define NTOK 4096

typedef __attribute__((ext_vector_type(8))) short bf16x8;
typedef __attribute__((ext_vector_type(4))) float f32x4;

__device__ __forceinline__ short to_bf16(float f) {
  unsigned u = __float_as_uint(f);
  unsigned r = (u + 0x7fffu + ((u >> 16) & 1u)) >> 16;   // RNE
  return (short)r;
}

__device__ __forceinline__ void gl16(const void* g, void* l) {
  __builtin_amdgcn_global_load_lds(
      (const __attribute__((address_space(1))) unsigned*)g,
      (__attribute__((address_space(3))) unsigned*)l, 16, 0, 0);
}

#define DSB do { __builtin_amdgcn_s_barrier(); __builtin_amdgcn_sched_barrier(0); } while (0)

// exact-enough GELU: A&S 7.1.26 erf (abs err 1.5e-7 << bf16 rounding)
__device__ __forceinline__ float fast_gelu(float v) {
  float x  = fabsf(v) * 0.70710678118f;
  float t  = __builtin_amdgcn_rcpf(fmaf(0.3275911f, x, 1.0f));
  float p  = t * fmaf(t, fmaf(t, fmaf(t, fmaf(t, 1.061405429f, -1.453152027f),
                                      1.421413741f), -0.284496736f), 0.254829592f);
  float ex = __expf(-x * x);
  float er = fmaf(-p, ex, 1.0f);
  er = (v < 0.f) ? -er : er;
  return 0.5f * v * (1.0f + er);
}

// ---------------- router: 64 tokens/block x 4 d-quarters ----------------
__global__ __launch_bounds__(256) void router_kernel(
    const float* __restrict__ x, const float* __restrict__ gw,
    int* __restrict__ cnt, float* __restrict__ psum,
    int* __restrict__ pairs, float* __restrict__ pairW)
{
  __shared__ float gws[DM * NE];
  __shared__ float part[3][64][NE];
  const int tid = threadIdx.x;
  for (int i = tid * 4; i < DM * NE; i += 256 * 4)
    *reinterpret_cast<float4*>(&gws[i]) = *reinterpret_cast<const float4*>(&gw[i]);
  __syncthreads();

  const int tok = tid & 63;
  const int q   = tid >> 6;                       // 0..3 d-quarter
  const int n   = blockIdx.x * 64 + tok;
  float acc[NE];
#pragma unroll
  for (int e = 0; e < NE; ++e) acc[e] = 0.f;

  const float4* xr = reinterpret_cast<const float4*>(x + (size_t)n * DM + q * 256);
  for (int d4 = 0; d4 < 64; ++d4) {
    float4 v = xr[d4];
    const float* gp = &gws[(q * 256 + d4 * 4) * NE];   // broadcast read (same addr all lanes)
    float xv;
#pragma unroll
    for (int dd = 0; dd < 4; ++dd) {
      xv = (dd == 0) ? v.x : (dd == 1) ? v.y : (dd == 2) ? v.z : v.w;
#pragma unroll
      for (int e = 0; e < NE; ++e) acc[e] = fmaf(xv, gp[dd * NE + e], acc[e]);
    }
  }

  if (q) {
#pragma unroll
    for (int e = 0; e < NE; ++e) part[q - 1][tok][e] = acc[e];
  }
  __syncthreads();
  if (q == 0) {
#pragma unroll
    for (int e = 0; e < NE; ++e)
      acc[e] += part[0][tok][e] + part[1][tok][e] + part[2][tok][e];

    float mx = acc[0];
#pragma unroll
    for (int e = 1; e < NE; ++e) mx = fmaxf(mx, acc[e]);
    float p[NE], s = 0.f;
#pragma unroll
    for (int e = 0; e < NE; ++e) { p[e] = expf(acc[e] - mx); s += p[e]; }
    float inv = 1.f / s;
#pragma unroll
    for (int e = 0; e < NE; ++e) {
      float v = p[e] * inv;
#pragma unroll
      for (int o = 32; o > 0; o >>= 1) v += __shfl_xor(v, o);
      if (tok == 0) atomicAdd(&psum[e], v);
    }

    float v0 = -1e30f, v1 = -1e30f; int i0 = 0, i1 = 0;
#pragma unroll
    for (int e = 0; e < NE; ++e) {
      float l = acc[e];
      if (l > v0) { v1 = v0; i1 = i0; v0 = l; i0 = e; }
      else if (l > v1) { v1 = l; i1 = e; }
    }
    float e1 = expf(v1 - v0);
    float den = 1.f + e1;
    pairW[n * 2]     = 1.f / den;
    pairW[n * 2 + 1] = e1 / den;
    int p0 = atomicAdd(&cnt[i0], 1); pairs[i0 * NTOK + p0] = n * 2;
    int p1 = atomicAdd(&cnt[i1], 1); pairs[i1 * NTOK + p1] = n * 2 + 1;
  }
}

__global__ void finalize_kernel(const int* __restrict__ cnt, int* __restrict__ off,
                                const float* __restrict__ psum, float* __restrict__ aux)
{
  if (threadIdx.x == 0 && blockIdx.x == 0) {
    int o = 0;
    for (int e = 0; e < NE; ++e) { off[e] = o; o += cnt[e]; }
    off[NE] = o;
    float a = 0.f;
    for (int e = 0; e < NE; ++e) { float me = psum[e] * (1.f / NTOK); a += me * me; }
    aux[0] = a * (float)NE;
  }
}

// ---------------- prepass: x f32 -> bf16 ----------------
__global__ __launch_bounds__(256) void convert_x_kernel(
    const float* __restrict__ x, short* __restrict__ xb)
{
  const int i = (blockIdx.x * 256 + threadIdx.x) * 8;
  float4 a = *reinterpret_cast<const float4*>(&x[i]);
  float4 b = *reinterpret_cast<const float4*>(&x[i + 4]);
  union { short s[8]; bf16x8 v; } p;
  p.s[0]=to_bf16(a.x); p.s[1]=to_bf16(a.y); p.s[2]=to_bf16(a.z); p.s[3]=to_bf16(a.w);
  p.s[4]=to_bf16(b.x); p.s[5]=to_bf16(b.y); p.s[6]=to_bf16(b.z); p.s[7]=to_bf16(b.w);
  *reinterpret_cast<bf16x8*>(&xb[i]) = p.v;
}

// ---------------- prepass: transpose + convert weights ----------------
__global__ __launch_bounds__(256) void transpose_kernel(
    const float* __restrict__ w1, const float* __restrict__ w2,
    short* __restrict__ w1t, short* __restrict__ w2t)
{
  const int z = blockIdx.z;
  const float* src; short* dst; int R, C, rt, ct;
  if (z < 8) { src = w1 + (size_t)z * DM * DFF; dst = w1t + (size_t)z * DM * DFF;
               R = DM; C = DFF; ct = blockIdx.x; rt = blockIdx.y; }
  else       { src = w2 + (size_t)(z - 8) * DM * DFF; dst = w2t + (size_t)(z - 8) * DM * DFF;
               R = DFF; C = DM; ct = blockIdx.y; rt = blockIdx.x; }
  const int r0 = rt * 64, c0 = ct * 64;
  __shared__ float t[64][65];
  const int tid = threadIdx.x;
  {
    const int row = tid >> 4;
    const int col = (tid & 15) * 4;
#pragma unroll
    for (int it = 0; it < 4; ++it) {
      float4 v = *reinterpret_cast<const float4*>(&src[(size_t)(r0 + it * 16 + row) * C + c0 + col]);
      t[it * 16 + row][col]     = v.x;
      t[it * 16 + row][col + 1] = v.y;
      t[it * 16 + row][col + 2] = v.z;
      t[it * 16 + row][col + 3] = v.w;
    }
  }
  __syncthreads();
  {
    const int oc  = tid >> 3;
    const int orr = (tid & 7) * 8;
#pragma unroll
    for (int it = 0; it < 2; ++it) {
      union { short s[8]; bf16x8 v; } p;
#pragma unroll
      for (int j = 0; j < 8; ++j) p.s[j] = to_bf16(t[orr + j][it * 32 + oc]);
      *reinterpret_cast<bf16x8*>(&dst[(size_t)(c0 + it * 32 + oc) * R + r0 + orr]) = p.v;
    }
  }
}

// ======= 128x128xBK32 core: TRIPLE buffer, 1 barrier/iter, true depth-2 =======
// Issue order per wave: prologue STAGE(t0),STAGE(t1); iter t: vmcnt -> barrier ->
// STAGE(t+2 into buf (t+2)%3) -> ds_read buf t%3 -> MFMA.
// vmcnt ledger: at top of iter t outstanding = sets {t, t+1} = 8 -> vmcnt(4)
// lands set t (issued 2 iters earlier, ~2 iters of latency cover). Last iter
// vmcnt(0). Never drains mid-loop. Restage target buf (t+2)%3 == buf of t-1:
// safe, all waves' t-1 ds_reads are in VGPRs before they pass the barrier.
// LDS swizzle (proven, 0 conflicts): tile [64 pairs][8 chunks of 8 shorts],
// chunk (p,s) holds (row = 2p + ((s^(p&7))>>2), kchunk = (s^(p&7))&3).

#define GEMM_LOOP(NT)                                                              \
  f32x4 acc[4][4];                                                                 \
  _Pragma("unroll") for (int i = 0; i < 4; ++i)                                    \
    _Pragma("unroll") for (int j = 0; j < 4; ++j) acc[i][j] = (f32x4){0.f,0.f,0.f,0.f}; \
  STAGE(0, 0);                                                                     \
  STAGE(1, 32);                                                                    \
  {                                                                                \
    int cur = 0, stg = 2;                                                          \
    for (int t = 0; t < (NT); ++t) {                                               \
      if (t < (NT) - 1) { asm volatile("s_waitcnt vmcnt(4)" ::: "memory"); }       \
      else              { asm volatile("s_waitcnt vmcnt(0)" ::: "memory"); }       \
      DSB;                                                                         \
      if (t + 2 < (NT)) STAGE(stg, (t + 2) * 32);                                  \
      bf16x8 af[4], bfv[4];                                                        \
      _Pragma("unroll") for (int i = 0; i < 4; ++i)                                \
        af[i] = *reinterpret_cast<const bf16x8*>(&As[cur][ab + i * 512]);          \
      _Pragma("unroll") for (int j = 0; j < 4; ++j)                                \
        bfv[j] = *reinterpret_cast<const bf16x8*>(&Bs[cur][bb + j * 512]);         \
      _Pragma("unroll") for (int i = 0; i < 4; ++i)                                \
        _Pragma("unroll") for (int j = 0; j < 4; ++j)                              \
          acc[i][j] = __builtin_amdgcn_mfma_f32_16x16x32_bf16(af[i], bfv[j], acc[i][j], 0, 0, 0); \
      cur = (cur == 2) ? 0 : cur + 1;                                              \
      stg = (stg == 2) ? 0 : stg + 1;                                              \
    }                                                                              \
  }

// ======== GEMM1: h = gelu(gather(xb) @ w1t[e]^T) ========
__global__ __launch_bounds__(256) void gemm1_kernel(
    const short* __restrict__ xb, const short* __restrict__ w1t,
    const int* __restrict__ cnt, const int* __restrict__ off,
    const int* __restrict__ pairs, short* __restrict__ h)
{
  // bijective XCD swizzle, nwg=8192, chunk=1024 = one expert per XCD.
  // decode: mt inner(32), ft mid(32), e outer(8) -> resident blocks share
  // xb panels (8x256KB) and a few w1t panels -> all fits XCD L2.
  const int wg = (blockIdx.x & 7) * 1024 + (blockIdx.x >> 3);
  const int mt = wg & 31;
  const int ft = (wg >> 5) & 31;
  const int e  = wg >> 10;
  const int M  = cnt[e];
  const int m0 = mt * 128;
  if (m0 >= M) return;
  const int ff0  = ft * 128;
  const int base = off[e];

  __shared__ __attribute__((aligned(16))) short As[3][128 * 32];
  __shared__ __attribute__((aligned(16))) short Bs[3][128 * 32];

  const int tid  = threadIdx.x;
  const int lane = tid & 63;
  const int wv   = tid >> 6;
  const int wm   = wv >> 1;
  const int wn   = wv & 1;

  const short* gA[2]; const short* gB[2]; int ldo[2];
#pragma unroll
  for (int l = 0; l < 2; ++l) {
    const int n   = l * 256 + tid;
    const int p   = n >> 3;
    const int s   = n & 7;
    const int cip = s ^ (p & 7);
    const int row = p * 2 + (cip >> 2);
    const int kch = cip & 3;
    int gi = m0 + row; if (gi > M - 1) gi = M - 1;
    const int tok = pairs[e * NTOK + gi] >> 1;
    gA[l]  = xb + (size_t)tok * DM + kch * 8;
    gB[l]  = w1t + ((size_t)e * DFF + ff0 + row) * DM + kch * 8;
    ldo[l] = n * 8;
  }

#define STAGE(buf, k0) do { \
  gl16(gA[0] + (k0), &As[buf][ldo[0]]); \
  gl16(gA[1] + (k0), &As[buf][ldo[1]]); \
  gl16(gB[0] + (k0), &Bs[buf][ldo[0]]); \
  gl16(gB[1] + (k0), &Bs[buf][ldo[1]]); \
} while (0)

  const int lrw = lane & 15;
  const int sr  = ((((lane & 1) << 2) | (lane >> 4)) ^ ((lane & 15) >> 1)) * 8;
  const int ab  = (wm * 32 + (lrw >> 1)) * 64 + sr;
  const int bb  = (wn * 32 + (lrw >> 1)) * 64 + sr;

  GEMM_LOOP(32)
#undef STAGE

  const int erow0 = m0 + wm * 64 + (lane >> 4) * 4;
  const int ecol0 = ff0 + wn * 64 + (lane & 15);
#pragma unroll
  for (int i = 0; i < 4; ++i) {
#pragma unroll
    for (int r = 0; r < 4; ++r) {
      const int grow = erow0 + i * 16 + r;
      if (grow < M) {
        short* hp = h + (size_t)(base + grow) * DFF + ecol0;
#pragma unroll
        for (int j = 0; j < 4; ++j)
          hp[j * 16] = to_bf16(fast_gelu(acc[i][j][r]));
      }
    }
  }
}

// ======== GEMM2: out += w * (h @ w2t[e]^T), K=4096 ========
__global__ __launch_bounds__(256) void gemm2_kernel(
    const short* __restrict__ h, const short* __restrict__ w2t,
    const int* __restrict__ cnt, const int* __restrict__ off,
    const int* __restrict__ pairs, const float* __restrict__ pairW,
    float* __restrict__ out)
{
  // nwg=2048, chunk=256 = one expert per XCD; dt inner(8) -> h panel (1MB)
  // reused across the 8 dt blocks in L2; w2t set via L2/L3.
  const int wg = (blockIdx.x & 7) * 256 + (blockIdx.x >> 3);
  const int dt = wg & 7;
  const int mt = (wg >> 3) & 31;
  const int e  = wg >> 8;
  const int M  = cnt[e];
  const int m0 = mt * 128;
  if (m0 >= M) return;
  const int d0   = dt * 128;
  const int base = off[e];

  __shared__ __attribute__((aligned(16))) short As[3][128 * 32];
  __shared__ __attribute__((aligned(16))) short Bs[3][128 * 32];

  const int tid  = threadIdx.x;
  const int lane = tid & 63;
  const int wv   = tid >> 6;
  const int wm   = wv >> 1;
  const int wn   = wv & 1;

  const short* gA[2]; const short* gB[2]; int ldo[2];
#pragma unroll
  for (int l = 0; l < 2; ++l) {
    const int n   = l * 256 + tid;
    const int p   = n >> 3;
    const int s   = n & 7;
    const int cip = s ^ (p & 7);
    const int row = p * 2 + (cip >> 2);
    const int kch = cip & 3;
    int gi = m0 + row; if (gi > M - 1) gi = M - 1;
    gA[l]  = h + (size_t)(base + gi) * DFF + kch * 8;
    gB[l]  = w2t + ((size_t)e * DM + d0 + row) * DFF + kch * 8;
    ldo[l] = n * 8;
  }

#define STAGE(buf, k0) do { \
  gl16(gA[0] + (k0), &As[buf][ldo[0]]); \
  gl16(gA[1] + (k0), &As[buf][ldo[1]]); \
  gl16(gB[0] + (k0), &Bs[buf][ldo[0]]); \
  gl16(gB[1] + (k0), &Bs[buf][ldo[1]]); \
} while (0)

  const int lrw = lane & 15;
  const int sr  = ((((lane & 1) << 2) | (lane >> 4)) ^ ((lane & 15) >> 1)) * 8;
  const int ab  = (wm * 32 + (lrw >> 1)) * 64 + sr;
  const int bb  = (wn * 32 + (lrw >> 1)) * 64 + sr;

  GEMM_LOOP(128)
#undef STAGE

  const int erow0 = m0 + wm * 64 + (lane >> 4) * 4;
  const int ecol0 = d0 + wn * 64 + (lane & 15);
#pragma unroll
  for (int i = 0; i < 4; ++i) {
#pragma unroll
    for (int r = 0; r < 4; ++r) {
      const int grow = erow0 + i * 16 + r;
      if (grow < M) {
        const int pr    = pairs[e * NTOK + grow];
        const float wgt = pairW[pr];
        const int tok   = pr >> 1;
#pragma unroll
        for (int j = 0; j < 4; ++j)
          atomicAdd(&out[(size_t)tok * DM + ecol0 + j * 16], wgt * acc[i][j][r]);
      }
    }
  }
}

extern "C" void kernel_launch(void* const* d_in, const int* in_sizes, int n_in,
                              void* d_out, int out_size, void* d_ws, size_t ws_size,
                              hipStream_t stream)
{
  const float* x  = (const float*)d_in[0];
  const float* gw = (const float*)d_in[1];
  const float* w1 = (const float*)d_in[2];
  const float* w2 = (const float*)d_in[3];
  float* outf = (float*)d_out;

  int*   cnt   = (int*)d_ws;
  int*   off   = cnt + 8;
  float* psum  = (float*)(cnt + 20);
  int*   pairs = (int*)((char*)d_ws + 512);
  float* pairW = (float*)((char*)d_ws + 512 + NE * NTOK * 4);
  short* xb    = (short*)((char*)d_ws + (size_t)(1)  * (1 << 20));
  short* w1t   = (short*)((char*)d_ws + (size_t)(16) * (1 << 20));
  short* w2t   = (short*)((char*)d_ws + (size_t)(80) * (1 << 20));
  short* h     = (short*)((char*)d_ws + (size_t)(144)* (1 << 20));

  hipMemsetAsync(d_ws, 0, 512, stream);
  hipMemsetAsync(d_out, 0, (size_t)out_size * sizeof(float), stream);

  router_kernel<<<NTOK / 64, 256, 0, stream>>>(x, gw, cnt, psum, pairs, pairW);
  finalize_kernel<<<1, 64, 0, stream>>>(cnt, off, psum, outf + (size_t)NTOK * DM);
  convert_x_kernel<<<NTOK * DM / (256 * 8), 256, 0, stream>>>(x, xb);
  transpose_kernel<<<dim3(64, 16, 16), 256, 0, stream>>>(w1, w2, w1t, w2t);
  gemm1_kernel<<<8192, 256, 0, stream>>>(xb, w1t, cnt, off, pairs, h);
  gemm2_kernel<<<2048, 256, 0, stream>>>(h, w2t, cnt, off, pairs, pairW, outf);
}